// Round 2
// baseline (274.985 us; speedup 1.0000x reference)
//
#include <hip/hip_runtime.h>
#include <hip/hip_cooperative_groups.h>

namespace cg = cooperative_groups;

#define T_TOK 16384
#define H 2048
#define HV (H / 4)       // float4 per row = 512
#define NE 8
#define TPG 4            // tokens per wave
#define WPB 8            // waves per block (block = 512 threads)
#define ALPHA 0.01f
#define TOPK 2
#define NBLK 512         // grid size (512 blk * 8 waves * 4 tok = 16384)

#define GAS __attribute__((address_space(1)))
#define LAS __attribute__((address_space(3)))

// out layout (floats): [0, 2T) idx as float, [2T, 4T) weights, [4T] aux loss
// ws layout (floats):  per-block partials, ws[b*16 + e] = sum(scores_e),
//                      ws[b*16 + 8 + e] = topk count_e   (b in [0, NBLK))

#define COMPUTE_J(xr, jj)                                               \
    {                                                                   \
        _Pragma("unroll")                                               \
        for (int e = 0; e < NE; e++) {                                  \
            const float4 wr = wlv[e * HV + (jj) * 64 + lane];           \
            _Pragma("unroll")                                           \
            for (int t = 0; t < TPG; t++) {                             \
                acc[e][t] = fmaf(xr[t].x, wr.x, acc[e][t]);             \
                acc[e][t] = fmaf(xr[t].y, wr.y, acc[e][t]);             \
                acc[e][t] = fmaf(xr[t].z, wr.z, acc[e][t]);             \
                acc[e][t] = fmaf(xr[t].w, wr.w, acc[e][t]);             \
            }                                                           \
        }                                                               \
    }

// Shared main body: logits -> softmax -> top2 -> per-block partials in ws.
__device__ __forceinline__ void gate_main_body(
    const float* __restrict__ x, const float* __restrict__ w,
    float* __restrict__ out, float* __restrict__ ws,
    float* wl, float* s_part)
{
    const int tid  = threadIdx.x;
    const int lane = tid & 63;
    const int wave = tid >> 6;
    const int t0   = (blockIdx.x * WPB + wave) * TPG;

    const float4* __restrict__ xv = (const float4*)x;
    const float4* __restrict__ wv = (const float4*)w;
    const float4* xp = xv + (size_t)t0 * HV + lane;

    // Preload TWO x column-groups (8 KB/wave in flight) before the barrier so
    // their HBM latency hides under the w staging drain.
    float4 xa[TPG], xb[TPG];
#pragma unroll
    for (int t = 0; t < TPG; t++) xa[t] = xp[t * HV];
#pragma unroll
    for (int t = 0; t < TPG; t++) xb[t] = xp[t * HV + 64];

    // Stage w direct global->LDS (wave-uniform base + lane*16 — legal layout).
    float4* wl4 = (float4*)wl;
#pragma unroll
    for (int k = 0; k < 8; k++) {
        __builtin_amdgcn_global_load_lds(
            (const GAS void*)(wv + tid + k * 512),
            (LAS void*)(wl4 + tid + k * 512), 16, 0, 0);
    }
    __syncthreads();   // drains vmcnt: w in LDS, xa/xb in regs

    float acc[NE][TPG];
#pragma unroll
    for (int e = 0; e < NE; e++)
#pragma unroll
        for (int t = 0; t < TPG; t++) acc[e][t] = 0.f;

    const float4* wlv = (const float4*)wl;

    // K-loop: 8 column-groups of 64 float4. Depth-2 register double buffer;
    // prefetch j+2/j+3 into renamed temps (full unroll -> WAR-free renames).
#pragma unroll
    for (int j = 0; j < 8; j += 2) {
        float4 xn[TPG], xm[TPG];
        if (j + 2 < 8) {
#pragma unroll
            for (int t = 0; t < TPG; t++) xn[t] = xp[t * HV + (j + 2) * 64];
        }
        COMPUTE_J(xa, j);
        if (j + 3 < 8) {
#pragma unroll
            for (int t = 0; t < TPG; t++) xm[t] = xp[t * HV + (j + 3) * 64];
        }
        COMPUTE_J(xb, j + 1);
        if (j + 2 < 8) {
#pragma unroll
            for (int t = 0; t < TPG; t++) xa[t] = xn[t];
        }
        if (j + 3 < 8) {
#pragma unroll
            for (int t = 0; t < TPG; t++) xb[t] = xm[t];
        }
    }

    // tree-reduce each accumulator across the 64 lanes (all lanes end with sum)
#pragma unroll
    for (int e = 0; e < NE; e++)
#pragma unroll
        for (int t = 0; t < TPG; t++) {
            float v = acc[e][t];
#pragma unroll
            for (int off = 32; off >= 1; off >>= 1)
                v += __shfl_xor(v, off, 64);
            acc[e][t] = v;
        }

    // Every lane holds full logit sums for all TPG tokens -> uniform
    // softmax/top-2; lane t stores token t, all lanes build identical partials.
    float pi_loc[NE], cnt_loc[NE];
#pragma unroll
    for (int e = 0; e < NE; e++) { pi_loc[e] = 0.f; cnt_loc[e] = 0.f; }

#pragma unroll
    for (int t = 0; t < TPG; t++) {
        float l[NE];
#pragma unroll
        for (int e = 0; e < NE; e++) l[e] = acc[e][t];
        float m = l[0];
#pragma unroll
        for (int e = 1; e < NE; e++) m = fmaxf(m, l[e]);
        float s[NE];
        float sum = 0.f;
#pragma unroll
        for (int e = 0; e < NE; e++) { s[e] = __expf(l[e] - m); sum += s[e]; }
#pragma unroll
        for (int e = 0; e < NE; e++) s[e] = s[e] / sum;

        // top-2, ties -> lower index (strict > scan)
        float b1 = -1.f, b2 = -1.f;
        int   i1 = 0,    i2 = 0;
#pragma unroll
        for (int e = 0; e < NE; e++) {
            if (s[e] > b1) { b2 = b1; i2 = i1; b1 = s[e]; i1 = e; }
            else if (s[e] > b2) { b2 = s[e]; i2 = e; }
        }

        if (lane == t) {
            const int tok = t0 + t;
            ((float2*)out)[tok]               = make_float2((float)i1, (float)i2);
            ((float2*)(out + 2 * T_TOK))[tok] = make_float2(b1, b2);
        }
        // static-indexed accumulation (runtime cnt_loc[i1] would go to scratch)
#pragma unroll
        for (int e = 0; e < NE; e++) {
            pi_loc[e]  += s[e];
            cnt_loc[e] += ((i1 == e) ? 1.f : 0.f) + ((i2 == e) ? 1.f : 0.f);
        }
    }

    // atomics-free fold: lane 0 of each wave publishes its wave's partials
    if (lane == 0) {
#pragma unroll
        for (int e = 0; e < NE; e++) {
            s_part[wave * 16 + e]     = pi_loc[e];
            s_part[wave * 16 + 8 + e] = cnt_loc[e];
        }
    }
    __syncthreads();
    if (tid < 16) {
        float v = 0.f;
#pragma unroll
        for (int wv8 = 0; wv8 < WPB; wv8++) v += s_part[wv8 * 16 + tid];
        ws[blockIdx.x * 16 + tid] = v;
    }
}

// Fused cooperative kernel: main body -> grid sync -> block 0 computes aux.
__global__ __launch_bounds__(512, 4) void gate_fused(
    const float* __restrict__ x, const float* __restrict__ w,
    float* __restrict__ out, float* __restrict__ ws)
{
    __shared__ float wl[NE * H];          // 64 KB: whole gate weight, fp32
    __shared__ float s_part[WPB * 16];    // per-wave partials (no atomics)

    gate_main_body(x, w, out, ws, wl, s_part);

    cg::this_grid().sync();               // all ws partials visible

    if (blockIdx.x == 0) {
        const int tid  = threadIdx.x;
        const int lane = tid & 63;
        const int wave = tid >> 6;

        // 512 threads, 512 block-partials: exactly one each (coalesced float4).
        const float4* p = (const float4*)(ws + tid * 16);
        float4 a0 = p[0], a1 = p[1], a2 = p[2], a3 = p[3];
        float pi[NE]  = {a0.x, a0.y, a0.z, a0.w, a1.x, a1.y, a1.z, a1.w};
        float cnt[NE] = {a2.x, a2.y, a2.z, a2.w, a3.x, a3.y, a3.z, a3.w};

#pragma unroll
        for (int e = 0; e < NE; e++) {
#pragma unroll
            for (int off = 32; off >= 1; off >>= 1) {
                pi[e]  += __shfl_xor(pi[e],  off, 64);
                cnt[e] += __shfl_xor(cnt[e], off, 64);
            }
        }
        // grid sync already synchronized the block; s_part reusable
        if (lane == 0) {
#pragma unroll
            for (int e = 0; e < NE; e++) {
                s_part[wave * 16 + e]     = pi[e];
                s_part[wave * 16 + 8 + e] = cnt[e];
            }
        }
        __syncthreads();
        if (tid == 0) {
            float aux = 0.f;
#pragma unroll
            for (int e = 0; e < NE; e++) {
                float spi = 0.f, scnt = 0.f;
#pragma unroll
                for (int wv8 = 0; wv8 < WPB; wv8++) {
                    spi  += s_part[wv8 * 16 + e];
                    scnt += s_part[wv8 * 16 + 8 + e];
                }
                const float Pi = spi / (float)T_TOK;
                const float ce = scnt / (float)(T_TOK * TOPK);
                aux += Pi * ce * (float)NE;
            }
            out[4 * T_TOK] = aux * ALPHA;
        }
    }
}

// ---- fallback two-kernel path (used only if cooperative launch is refused) --

__global__ __launch_bounds__(512, 4) void gate_main(
    const float* __restrict__ x, const float* __restrict__ w,
    float* __restrict__ out, float* __restrict__ ws)
{
    __shared__ float wl[NE * H];
    __shared__ float s_part[WPB * 16];
    gate_main_body(x, w, out, ws, wl, s_part);
}

__global__ __launch_bounds__(256) void gate_aux(
    const float* __restrict__ ws, float* __restrict__ out)
{
    __shared__ float s_pi[NE];
    __shared__ float s_cnt[NE];
    const int tid = threadIdx.x;
    if (tid < NE) { s_pi[tid] = 0.f; s_cnt[tid] = 0.f; }
    __syncthreads();

    float pi[NE], cnt[NE];
#pragma unroll
    for (int e = 0; e < NE; e++) { pi[e] = 0.f; cnt[e] = 0.f; }

    for (int b = tid; b < NBLK; b += 256) {
        const float4* p = (const float4*)(ws + b * 16);
        float4 a0 = p[0], a1 = p[1], a2 = p[2], a3 = p[3];
        pi[0] += a0.x; pi[1] += a0.y; pi[2] += a0.z; pi[3] += a0.w;
        pi[4] += a1.x; pi[5] += a1.y; pi[6] += a1.z; pi[7] += a1.w;
        cnt[0] += a2.x; cnt[1] += a2.y; cnt[2] += a2.z; cnt[3] += a2.w;
        cnt[4] += a3.x; cnt[5] += a3.y; cnt[6] += a3.z; cnt[7] += a3.w;
    }

#pragma unroll
    for (int e = 0; e < NE; e++) {
#pragma unroll
        for (int off = 32; off >= 1; off >>= 1) {
            pi[e]  += __shfl_xor(pi[e],  off, 64);
            cnt[e] += __shfl_xor(cnt[e], off, 64);
        }
    }
    if ((tid & 63) == 0) {
#pragma unroll
        for (int e = 0; e < NE; e++) {
            atomicAdd(&s_pi[e],  pi[e]);
            atomicAdd(&s_cnt[e], cnt[e]);
        }
    }
    __syncthreads();

    if (tid == 0) {
        float aux = 0.f;
#pragma unroll
        for (int e = 0; e < NE; e++) {
            const float Pi = s_pi[e] / (float)T_TOK;
            const float ce = s_cnt[e] / (float)(T_TOK * TOPK);
            aux += Pi * ce * (float)NE;
        }
        out[4 * T_TOK] = aux * ALPHA;
    }
}

extern "C" void kernel_launch(void* const* d_in, const int* in_sizes, int n_in,
                              void* d_out, int out_size, void* d_ws, size_t ws_size,
                              hipStream_t stream) {
    const float* x = (const float*)d_in[0];
    const float* w = (const float*)d_in[1];
    float* out = (float*)d_out;
    float* ws  = (float*)d_ws;

    void* args[] = {(void*)&x, (void*)&w, (void*)&out, (void*)&ws};
    hipError_t err = hipLaunchCooperativeKernel(
        (const void*)gate_fused, dim3(NBLK), dim3(512), args, 0, stream);
    if (err != hipSuccess) {
        // co-residency or capture refusal: proven two-kernel path
        gate_main<<<NBLK, 512, 0, stream>>>(x, w, out, ws);
        gate_aux<<<1, 256, 0, stream>>>(ws, out);
    }
}

// Round 3
// 200.747 us; speedup vs baseline: 1.3698x; 1.3698x over previous
//
#include <hip/hip_runtime.h>

#define T_TOK 16384
#define H 2048
#define HV (H / 4)       // float4 per row = 512
#define NE 8
#define TPG 4            // tokens per wave
#define WPB 8            // waves per block (block = 512 threads)
#define ALPHA 0.01f
#define TOPK 2
#define NBLK 512         // gate_main grid size (512 blk * 8 waves * 4 tok = 16384)

#define GAS __attribute__((address_space(1)))
#define LAS __attribute__((address_space(3)))

// out layout (floats): [0, 2T) idx as float, [2T, 4T) weights, [4T] aux loss
// ws layout (floats):  per-block partials, ws[b*16 + e] = sum(scores_e),
//                      ws[b*16 + 8 + e] = topk count_e   (b in [0, NBLK))

#define COMPUTE_J(xr, jj)                                               \
    {                                                                   \
        _Pragma("unroll")                                               \
        for (int e = 0; e < NE; e++) {                                  \
            const float4 wr = wlv[e * HV + (jj) * 64 + lane];           \
            _Pragma("unroll")                                           \
            for (int t = 0; t < TPG; t++) {                             \
                acc[e][t] = fmaf(xr[t].x, wr.x, acc[e][t]);             \
                acc[e][t] = fmaf(xr[t].y, wr.y, acc[e][t]);             \
                acc[e][t] = fmaf(xr[t].z, wr.z, acc[e][t]);             \
                acc[e][t] = fmaf(xr[t].w, wr.w, acc[e][t]);             \
            }                                                           \
        }                                                               \
    }

__global__ __launch_bounds__(512, 4) void gate_main(
    const float* __restrict__ x, const float* __restrict__ w,
    float* __restrict__ out, float* __restrict__ ws)
{
    __shared__ float wl[NE * H];          // 64 KB: whole gate weight, fp32
    __shared__ float s_part[WPB * 16];    // per-wave partials (no atomics)

    const int tid  = threadIdx.x;
    const int lane = tid & 63;
    const int wave = tid >> 6;
    const int t0   = (blockIdx.x * WPB + wave) * TPG;

    const float4* __restrict__ xv = (const float4*)x;
    const float4* __restrict__ wv = (const float4*)w;
    const float4* xp = xv + (size_t)t0 * HV + lane;

    // Preload TWO x column-groups (8 KB/wave in flight) before the barrier so
    // their HBM latency hides under the w staging drain.
    float4 xa[TPG], xb[TPG];
#pragma unroll
    for (int t = 0; t < TPG; t++) xa[t] = xp[t * HV];
#pragma unroll
    for (int t = 0; t < TPG; t++) xb[t] = xp[t * HV + 64];

    // Stage w direct global->LDS (no VGPR round-trip, no ds_writes).
    // Dest = wave-uniform base + lane*16 (linear), which is exactly the
    // global_load_lds write pattern; source is the matching per-lane address.
    float4* wl4 = (float4*)wl;
#pragma unroll
    for (int k = 0; k < 8; k++) {
        __builtin_amdgcn_global_load_lds(
            (const GAS void*)(wv + tid + k * 512),
            (LAS void*)(wl4 + tid + k * 512), 16, 0, 0);
    }
    __syncthreads();   // drains vmcnt: w in LDS, xa/xb in regs

    float acc[NE][TPG];
#pragma unroll
    for (int e = 0; e < NE; e++)
#pragma unroll
        for (int t = 0; t < TPG; t++) acc[e][t] = 0.f;

    const float4* wlv = (const float4*)wl;

    // K-loop: 8 column-groups of 64 float4. Depth-2 register double buffer;
    // prefetch j+2/j+3 into renamed temps (full unroll -> WAR-free renames).
#pragma unroll
    for (int j = 0; j < 8; j += 2) {
        float4 xn[TPG], xm[TPG];
        if (j + 2 < 8) {
#pragma unroll
            for (int t = 0; t < TPG; t++) xn[t] = xp[t * HV + (j + 2) * 64];
        }
        COMPUTE_J(xa, j);
        if (j + 3 < 8) {
#pragma unroll
            for (int t = 0; t < TPG; t++) xm[t] = xp[t * HV + (j + 3) * 64];
        }
        COMPUTE_J(xb, j + 1);
        if (j + 2 < 8) {
#pragma unroll
            for (int t = 0; t < TPG; t++) xa[t] = xn[t];
        }
        if (j + 3 < 8) {
#pragma unroll
            for (int t = 0; t < TPG; t++) xb[t] = xm[t];
        }
    }

    // tree-reduce each accumulator across the 64 lanes (all lanes end with sum)
#pragma unroll
    for (int e = 0; e < NE; e++)
#pragma unroll
        for (int t = 0; t < TPG; t++) {
            float v = acc[e][t];
#pragma unroll
            for (int off = 32; off >= 1; off >>= 1)
                v += __shfl_xor(v, off, 64);
            acc[e][t] = v;
        }

    // After the butterfly EVERY lane holds the full logit sums for all TPG
    // tokens, so all lanes compute identical softmax/top-2 (uniform, no
    // divergence); lane t stores token t, lane 0 accumulates block partials.
    float pi_loc[NE], cnt_loc[NE];
#pragma unroll
    for (int e = 0; e < NE; e++) { pi_loc[e] = 0.f; cnt_loc[e] = 0.f; }

#pragma unroll
    for (int t = 0; t < TPG; t++) {
        float l[NE];
#pragma unroll
        for (int e = 0; e < NE; e++) l[e] = acc[e][t];
        float m = l[0];
#pragma unroll
        for (int e = 1; e < NE; e++) m = fmaxf(m, l[e]);
        float s[NE];
        float sum = 0.f;
#pragma unroll
        for (int e = 0; e < NE; e++) { s[e] = __expf(l[e] - m); sum += s[e]; }
#pragma unroll
        for (int e = 0; e < NE; e++) s[e] = s[e] / sum;

        // top-2, ties -> lower index (strict > scan)
        float b1 = -1.f, b2 = -1.f;
        int   i1 = 0,    i2 = 0;
#pragma unroll
        for (int e = 0; e < NE; e++) {
            if (s[e] > b1) { b2 = b1; i2 = i1; b1 = s[e]; i1 = e; }
            else if (s[e] > b2) { b2 = s[e]; i2 = e; }
        }

        if (lane == t) {
            const int tok = t0 + t;
            ((float2*)out)[tok]               = make_float2((float)i1, (float)i2);
            ((float2*)(out + 2 * T_TOK))[tok] = make_float2(b1, b2);
        }
        // static-indexed accumulation (runtime cnt_loc[i1] would go to scratch)
#pragma unroll
        for (int e = 0; e < NE; e++) {
            pi_loc[e]  += s[e];
            cnt_loc[e] += ((i1 == e) ? 1.f : 0.f) + ((i2 == e) ? 1.f : 0.f);
        }
    }

    // atomics-free fold: lane 0 of each wave publishes its wave's partials
    if (lane == 0) {
#pragma unroll
        for (int e = 0; e < NE; e++) {
            s_part[wave * 16 + e]     = pi_loc[e];
            s_part[wave * 16 + 8 + e] = cnt_loc[e];
        }
    }
    __syncthreads();
    if (tid < 16) {
        float v = 0.f;
#pragma unroll
        for (int wv8 = 0; wv8 < WPB; wv8++) v += s_part[wv8 * 16 + tid];
        ws[blockIdx.x * 16 + tid] = v;
    }
}

__global__ __launch_bounds__(256) void gate_aux(
    const float* __restrict__ ws, float* __restrict__ out)
{
    __shared__ float s_pi[NE];
    __shared__ float s_cnt[NE];
    const int tid = threadIdx.x;
    if (tid < NE) { s_pi[tid] = 0.f; s_cnt[tid] = 0.f; }
    __syncthreads();

    float pi[NE], cnt[NE];
#pragma unroll
    for (int e = 0; e < NE; e++) { pi[e] = 0.f; cnt[e] = 0.f; }

    for (int b = tid; b < NBLK; b += 256) {
        const float4* p = (const float4*)(ws + b * 16);
        float4 a0 = p[0], a1 = p[1], a2 = p[2], a3 = p[3];
        pi[0] += a0.x; pi[1] += a0.y; pi[2] += a0.z; pi[3] += a0.w;
        pi[4] += a1.x; pi[5] += a1.y; pi[6] += a1.z; pi[7] += a1.w;
        cnt[0] += a2.x; cnt[1] += a2.y; cnt[2] += a2.z; cnt[3] += a2.w;
        cnt[4] += a3.x; cnt[5] += a3.y; cnt[6] += a3.z; cnt[7] += a3.w;
    }

#pragma unroll
    for (int e = 0; e < NE; e++) {
#pragma unroll
        for (int off = 32; off >= 1; off >>= 1) {
            pi[e]  += __shfl_xor(pi[e],  off, 64);
            cnt[e] += __shfl_xor(cnt[e], off, 64);
        }
    }
    if ((tid & 63) == 0) {
#pragma unroll
        for (int e = 0; e < NE; e++) {
            atomicAdd(&s_pi[e],  pi[e]);
            atomicAdd(&s_cnt[e], cnt[e]);
        }
    }
    __syncthreads();

    if (tid == 0) {
        float aux = 0.f;
#pragma unroll
        for (int e = 0; e < NE; e++) {
            const float Pi = s_pi[e] / (float)T_TOK;
            const float ce = s_cnt[e] / (float)(T_TOK * TOPK);
            aux += Pi * ce * (float)NE;
        }
        out[4 * T_TOK] = aux * ALPHA;
    }
}

extern "C" void kernel_launch(void* const* d_in, const int* in_sizes, int n_in,
                              void* d_out, int out_size, void* d_ws, size_t ws_size,
                              hipStream_t stream) {
    const float* x = (const float*)d_in[0];
    const float* w = (const float*)d_in[1];
    float* out = (float*)d_out;
    float* ws  = (float*)d_ws;

    gate_main<<<NBLK, 512, 0, stream>>>(x, w, out, ws);
    gate_aux<<<1, 256, 0, stream>>>(ws, out);
}